// Round 11
// baseline (365.537 us; speedup 1.0000x reference)
//
#include <hip/hip_runtime.h>
#include <math.h>

#define SEQLEN 2048
#define DIN 2048
#define NH 32
#define NKV 8
#define HD 64
#define DQ (NH*HD)    // 2048
#define DKV (NKV*HD)  // 512

using u16 = unsigned short;
using u32 = unsigned int;
using bf16x8 = __attribute__((ext_vector_type(8))) __bf16;
using f32x4  = __attribute__((ext_vector_type(4))) float;

__device__ __forceinline__ u16 f2b(float f) {
    union { float f; u32 u; } x; x.f = f;
    u32 u = x.u;
    u32 r = (u + 0x7fffu + ((u >> 16) & 1u)) >> 16;   // RNE
    return (u16)r;
}
__device__ __forceinline__ float b2f(u16 h) {
    union { u32 u; float f; } x; x.u = (u32)h << 16; return x.f;
}
__device__ __forceinline__ u32 fbits(float f) {
    union { float f; u32 u; } x; x.f = f; return x.u;
}

// async global->LDS, 16B/lane; lds base wave-uniform, lane i writes i*16B.
__device__ __forceinline__ void gl2lds16(const u16* g, u16* l) {
    __builtin_amdgcn_global_load_lds(
        (const __attribute__((address_space(1))) void*)g,
        (__attribute__((address_space(3))) void*)l,
        16, 0, 0);
}

// --- 16-row x 32-k chunks (512 u16) for GEMM tiles --------------------------
__device__ __forceinline__ int lds_off32(int row, int kk0) {
    return (row >> 4) * 512 + (kk0 >> 3) * 128 + (row & 15) * 8;
}

// ---------------------------------------------------------------------------
// Fused prep: cast x -> bf16; transpose-cast wq/wk/wv (contiguous [3072][2048])
// and wo.
// ---------------------------------------------------------------------------
__global__ __launch_bounds__(256) void prep(const float* __restrict__ x,
                                            const float* __restrict__ wq,
                                            const float* __restrict__ wk,
                                            const float* __restrict__ wv,
                                            const float* __restrict__ wo,
                                            u16* __restrict__ xb,
                                            u16* __restrict__ wqkvT,
                                            u16* __restrict__ woT) {
    const int b = blockIdx.x;
    const int t = threadIdx.x;
    if (b < 4096) {
        int i = b * 1024 + t * 4;
        float4 v = *reinterpret_cast<const float4*>(&x[i]);
        ushort4 o;
        o.x = f2b(v.x); o.y = f2b(v.y); o.z = f2b(v.z); o.w = f2b(v.w);
        *reinterpret_cast<ushort4*>(&xb[i]) = o;
        return;
    }
    __shared__ float tile[32][33];
    int b2 = b - 4096;
    const float* src; u16* dst; int C, bx, by;
    if (b2 < 4096)      { src = wq; dst = wqkvT;                           C = 2048; bx = b2 & 63; by = b2 >> 6; }
    else if (b2 < 5120) { b2 -= 4096; src = wk; dst = wqkvT + (size_t)2048 * 2048; C = 512; bx = b2 & 15; by = b2 >> 4; }
    else if (b2 < 6144) { b2 -= 5120; src = wv; dst = wqkvT + (size_t)2560 * 2048; C = 512; bx = b2 & 15; by = b2 >> 4; }
    else                { b2 -= 6144; src = wo; dst = woT;                 C = 2048; bx = b2 & 63; by = b2 >> 6; }
    const int c0 = bx * 32, r0 = by * 32;
    const int tr = t >> 5, tc = t & 31;
    #pragma unroll
    for (int i = 0; i < 4; ++i)
        tile[tr + i * 8][tc] = src[(size_t)(r0 + tr + i * 8) * C + c0 + tc];
    __syncthreads();
    #pragma unroll
    for (int i = 0; i < 4; ++i)
        dst[(size_t)(c0 + tr + i * 8) * 2048 + r0 + tc] = f2b(tile[tc][tr + i * 8]);
}

// ---------------------------------------------------------------------------
// QKV GEMM v10 (verified 58.4us): SPLIT-K=2 thick loop with BF16 partials.
// BM=BN=128, 16 MFMA + 8 b128 ds_read per wave-step, counted depth-2 (3
// bufs). Grid (24,16,2)=768 = 3/CU.
// ---------------------------------------------------------------------------
__global__ __launch_bounds__(256) void gemm_splitk(const u16* __restrict__ A,
                                                   const u16* __restrict__ Bt,
                                                   u16* __restrict__ P) {
    __shared__ u16 As[3][128 * 32];   // 3 bufs x 8KB
    __shared__ u16 Bs[3][128 * 32];   // 3 bufs x 8KB  (48KB total)
    const int t = threadIdx.x;
    const int w = t >> 6, lane = t & 63, quad = lane >> 4, l15 = lane & 15;
    const int m0 = blockIdx.y * 128, n0 = blockIdx.x * 128;
    const int kb = blockIdx.z << 10;                 // 0 or 1024
    u16* Cp = P + (size_t)blockIdx.z * (2048 * 3072);
    const int wr = (w >> 1) * 64, wc = (w & 1) * 64;
    const int srow = lane & 15, skoct = (lane >> 4) * 8;
    const int K = 2048, N = 3072;

    f32x4 acc[4][4];
    #pragma unroll
    for (int mt = 0; mt < 4; ++mt)
        #pragma unroll
        for (int nt = 0; nt < 4; ++nt)
            #pragma unroll
            for (int r = 0; r < 4; ++r) acc[mt][nt][r] = 0.0f;

    auto stage = [&](int buf, int st) {
        const int k0 = st << 5;
        #pragma unroll
        for (int i = 0; i < 2; ++i) {
            int c = w * 2 + i;
            gl2lds16(A  + (size_t)(m0 + c * 16 + srow) * K + kb + k0 + skoct, &As[buf][c * 512]);
            gl2lds16(Bt + (size_t)(n0 + c * 16 + srow) * K + kb + k0 + skoct, &Bs[buf][c * 512]);
        }
    };

    const int nsteps = 32;                           // K/2 / 32
    stage(0, 0);
    stage(1, 1);
    int cur = 0;
    for (int st = 0; st < nsteps; ++st) {
        if (st < nsteps - 1) asm volatile("s_waitcnt vmcnt(4)" ::: "memory");
        else                 asm volatile("s_waitcnt vmcnt(0)" ::: "memory");
        __builtin_amdgcn_s_barrier();
        asm volatile("" ::: "memory");               // no ds_read hoist
        if (st + 2 < nsteps) {
            int tgt = (cur == 0) ? 2 : cur - 1;      // buf (st+2)%3, read at st-1
            stage(tgt, st + 2);
        }
        const int kk0 = quad * 8;
        bf16x8 a[4], b[4];
        #pragma unroll
        for (int mt = 0; mt < 4; ++mt)
            a[mt] = *reinterpret_cast<const bf16x8*>(&As[cur][lds_off32(wr + mt * 16 + l15, kk0)]);
        #pragma unroll
        for (int nt = 0; nt < 4; ++nt)
            b[nt] = *reinterpret_cast<const bf16x8*>(&Bs[cur][lds_off32(wc + nt * 16 + l15, kk0)]);
        #pragma unroll
        for (int mt = 0; mt < 4; ++mt)
            #pragma unroll
            for (int nt = 0; nt < 4; ++nt)
                acc[mt][nt] = __builtin_amdgcn_mfma_f32_16x16x32_bf16(a[mt], b[nt], acc[mt][nt], 0, 0, 0);
        cur = (cur == 2) ? 0 : cur + 1;
    }

    #pragma unroll
    for (int mt = 0; mt < 4; ++mt)
        #pragma unroll
        for (int nt = 0; nt < 4; ++nt) {
            const int rb  = m0 + wr + mt * 16 + quad * 4;
            const int col = n0 + wc + nt * 16 + l15;
            #pragma unroll
            for (int r = 0; r < 4; ++r)
                Cp[(size_t)(rb + r) * N + col] = f2b(acc[mt][nt][r]);
        }
}

// ---------------------------------------------------------------------------
// qkv_reduce (verified): bf16 P0+P1 -> fused RMSNorm+RoPE (Q/K) or
// interleave-transpose (V). Grid (32 s-tiles, 48 heads), 256 thr.
// ---------------------------------------------------------------------------
__global__ __launch_bounds__(256) void qkv_reduce(const u16* __restrict__ P,
                                                  u16* __restrict__ Qb,
                                                  u16* __restrict__ Kb,
                                                  u16* __restrict__ VtG,
                                                  const float* __restrict__ cosb,
                                                  const float* __restrict__ sinb,
                                                  const float* __restrict__ qnw,
                                                  const float* __restrict__ knw) {
    __shared__ u16 Vl[64][64];
    const int s0 = blockIdx.x * 64;
    const int h  = blockIdx.y;                    // 0..31 Q, 32..39 K, 40..47 V
    const int t  = threadIdx.x;
    const int r  = t >> 2, q = t & 3;
    const int s  = s0 + r;

    const u16* p0 = P + (size_t)s * 3072 + h * 64 + q * 16;
    const u16* p1 = p0 + (size_t)2048 * 3072;
    float v[16];
    #pragma unroll
    for (int c = 0; c < 2; ++c) {
        uint4 a = *reinterpret_cast<const uint4*>(p0 + c * 8);
        uint4 b = *reinterpret_cast<const uint4*>(p1 + c * 8);
        const u32* aw = reinterpret_cast<const u32*>(&a);
        const u32* bw = reinterpret_cast<const u32*>(&b);
        #pragma unroll
        for (int j = 0; j < 4; ++j) {
            v[c*8 + j*2]     = b2f((u16)(aw[j] & 0xffffu)) + b2f((u16)(bw[j] & 0xffffu));
            v[c*8 + j*2 + 1] = b2f((u16)(aw[j] >> 16))     + b2f((u16)(bw[j] >> 16));
        }
    }

    if (h >= 40) {                                // ---- V ----
        const int a4 = (r >> 4) & 3, b4 = (r >> 2) & 3;
        const int cl = (b4 * 2 + (a4 >> 1)) * 8 + (a4 & 1) * 4 + (r & 3);
        #pragma unroll
        for (int i = 0; i < 16; ++i) Vl[q * 16 + i][cl] = f2b(v[i]);
        __syncthreads();
        u16* dst = VtG + (size_t)((h - 40) * 64 + r) * 2048 + s0 + q * 16;
        #pragma unroll
        for (int i = 0; i < 4; ++i)
            *reinterpret_cast<ushort4*>(dst + i * 4) =
                *reinterpret_cast<const ushort4*>(&Vl[r][q * 16 + i * 4]);
        return;
    }

    const bool isQ = h < 32;
    const float* nw = isQ ? qnw : knw;
    float s2 = 0.0f;
    #pragma unroll
    for (int i = 0; i < 16; ++i) s2 += v[i] * v[i];
    s2 += __shfl_xor(s2, 1);
    s2 += __shfl_xor(s2, 2);
    const float rin = rsqrtf(s2 * (1.0f / 64.0f) + 1e-6f);

    float vn[16];
    #pragma unroll
    for (int i = 0; i < 16; ++i) vn[i] = v[i] * rin * nw[q * 16 + i];

    const float sgn = (q < 2) ? -1.0f : 1.0f;     // rotate_half sign
    float res[16];
    #pragma unroll
    for (int i = 0; i < 16; ++i) {
        const int d = q * 16 + i;
        float c  = cosb[s * 64 + d];
        float sn = sinb[s * 64 + d];
        float vp = __shfl_xor(vn[i], 2);          // partner d^32
        res[i] = vn[i] * c + sgn * vp * sn;
    }

    u16* dst;
    if (isQ) {
        #pragma unroll
        for (int i = 0; i < 16; ++i) res[i] *= 0.18033688f;   // 0.125*log2(e)
        dst = Qb + (size_t)s * 2048 + h * 64 + q * 16;
    } else {
        dst = Kb + (size_t)s * 512 + (h - 32) * 64 + q * 16;
    }
    #pragma unroll
    for (int i = 0; i < 4; ++i) {
        ushort4 o;
        o.x = f2b(res[i*4+0]); o.y = f2b(res[i*4+1]);
        o.z = f2b(res[i*4+2]); o.w = f2b(res[i*4+3]);
        *reinterpret_cast<ushort4*>(dst + i * 4) = o;
    }
}

// ---------------------------------------------------------------------------
// Out-projection GEMM (r8/r10-verbatim). BM=64, BN=128, counted depth-2 (3
// bufs), grid (16,32) = 512 = 2/CU, fp32 C direct to out.
// ---------------------------------------------------------------------------
__global__ __launch_bounds__(256) void gemm_out(const u16* __restrict__ A,
                                                const u16* __restrict__ Bt,
                                                float* __restrict__ Cf) {
    __shared__ u16 As[3][64 * 32];    // 3 x 4KB
    __shared__ u16 Bs[3][128 * 32];   // 3 x 8KB  (36KB total)
    const int t = threadIdx.x;
    const int w = t >> 6, lane = t & 63, quad = lane >> 4, l15 = lane & 15;
    const int m0 = blockIdx.y * 64, n0 = blockIdx.x * 128;
    const int wr = (w >> 1) * 32, wc = (w & 1) * 64;
    const int srow = lane & 15, skoct = (lane >> 4) * 8;
    const int K = 2048, N = 2048;

    f32x4 acc[2][4];
    #pragma unroll
    for (int mt = 0; mt < 2; ++mt)
        #pragma unroll
        for (int nt = 0; nt < 4; ++nt)
            #pragma unroll
            for (int r = 0; r < 4; ++r) acc[mt][nt][r] = 0.0f;

    auto stage = [&](int buf, int st) {
        const int k0 = st << 5;
        gl2lds16(A + (size_t)(m0 + w * 16 + srow) * K + k0 + skoct, &As[buf][w * 512]);
        #pragma unroll
        for (int i = 0; i < 2; ++i) {
            int c = w * 2 + i;
            gl2lds16(Bt + (size_t)(n0 + c * 16 + srow) * K + k0 + skoct, &Bs[buf][c * 512]);
        }
    };

    const int nsteps = K >> 5;                       // 64
    stage(0, 0);
    stage(1, 1);
    int cur = 0;
    for (int st = 0; st < nsteps; ++st) {
        if (st < nsteps - 1) asm volatile("s_waitcnt vmcnt(3)" ::: "memory");
        else                 asm volatile("s_waitcnt vmcnt(0)" ::: "memory");
        __builtin_amdgcn_s_barrier();
        asm volatile("" ::: "memory");
        if (st + 2 < nsteps) {
            int tgt = (cur == 0) ? 2 : cur - 1;
            stage(tgt, st + 2);
        }
        const int kk0 = quad * 8;
        bf16x8 a[2], b[4];
        #pragma unroll
        for (int mt = 0; mt < 2; ++mt)
            a[mt] = *reinterpret_cast<const bf16x8*>(&As[cur][lds_off32(wr + mt * 16 + l15, kk0)]);
        #pragma unroll
        for (int nt = 0; nt < 4; ++nt)
            b[nt] = *reinterpret_cast<const bf16x8*>(&Bs[cur][lds_off32(wc + nt * 16 + l15, kk0)]);
        #pragma unroll
        for (int mt = 0; mt < 2; ++mt)
            #pragma unroll
            for (int nt = 0; nt < 4; ++nt)
                acc[mt][nt] = __builtin_amdgcn_mfma_f32_16x16x32_bf16(a[mt], b[nt], acc[mt][nt], 0, 0, 0);
        cur = (cur == 2) ? 0 : cur + 1;
    }

    #pragma unroll
    for (int mt = 0; mt < 2; ++mt)
        #pragma unroll
        for (int nt = 0; nt < 4; ++nt) {
            const int rb  = m0 + wr + mt * 16 + quad * 4;
            const int col = n0 + wc + nt * 16 + l15;
            #pragma unroll
            for (int r = 0; r < 4; ++r)
                Cf[(size_t)(rb + r) * N + col] = acc[mt][nt][r];
        }
}

// ---------------------------------------------------------------------------
// MFMA flash attention v8: ZERO-LDS, BARRIER-FREE. Rationale (r10 counters):
// attn was occupancy-bound (Occ 11.8%, MfmaUtil 9.5%, HBM 2.6%) -- LDS
// staging capped residency and paired blocks left CUs half-idle. Per-XCD
// K/V working set is 512KB (kvh = b&7 == XCD under round-robin) -> L2/L1
// resident, so staging is pure overhead (guide common-mistake #7 / m169).
// v8: 1024 one-head blocks (heavy-first LPT backfill), 4 independent waves
// per block (no __syncthreads anywhere); each wave reads K/V MFMA fragments
// DIRECTLY from global (16B/lane contiguous, L1-hit after first wave).
// K frag: Kb[(k0+kt4*16+l15)*DKV + kvh*HD + kk0] (8 contiguous bf16).
// V frag: VtG[(kvh*HD+dt*16+l15)*2048 + k0 + kk0] (column-interleaved layout
// built by qkv_reduce -> full-K=32 PV MFMAs). Fixed-shift softmax
// p=exp2(s-24).
// ---------------------------------------------------------------------------
__global__ __launch_bounds__(256) void attn_fused(const u16* __restrict__ Qb,
                                                  const u16* __restrict__ Kb,
                                                  const u16* __restrict__ VtG,
                                                  u16* __restrict__ attnb) {
    const int b    = blockIdx.x;               // 1024 blocks
    const int kvh  = b & 7;                    // == XCD (round-robin)
    const int qt   = 31 - (b >> 5);            // heavy-first
    const int q0   = qt * 64;
    const int h    = kvh * 4 + ((b >> 3) & 3);
    const int t    = threadIdx.x;
    const int w    = t >> 6, lane = t & 63, quad = lane >> 4, l15 = lane & 15;
    const int qrow = q0 + w * 16 + l15;

    const u16* qr = Qb + (size_t)qrow * DQ + h * HD;
    bf16x8 qB0, qB1;
    qB0 = *reinterpret_cast<const bf16x8*>(qr + quad * 8);
    qB1 = *reinterpret_cast<const bf16x8*>(qr + 32 + quad * 8);

    const u16* Kh = Kb  + kvh * HD;                      // [2048][512] + head
    const u16* Vh = VtG + (size_t)kvh * HD * 2048;       // [64][2048] interleaved

    f32x4 o[4];
    #pragma unroll
    for (int dt = 0; dt < 4; ++dt)
        #pragma unroll
        for (int r = 0; r < 4; ++r) o[dt][r] = 0.0f;
    float lpart = 0.0f;

    for (int kt = 0; kt <= qt; ++kt) {
        const int k0 = kt * 64;

        // S^T = K . Q^T  (16 q x 64 kv per wave), K frags direct from L1/L2
        f32x4 s[4];
        #pragma unroll
        for (int kt4 = 0; kt4 < 4; ++kt4)
            #pragma unroll
            for (int r = 0; r < 4; ++r) s[kt4][r] = 0.0f;
        #pragma unroll
        for (int ks = 0; ks < 2; ++ks) {
            const int kk0 = ks * 32 + quad * 8;
            #pragma unroll
            for (int kt4 = 0; kt4 < 4; ++kt4) {
                bf16x8 ka = *reinterpret_cast<const bf16x8*>(
                    &Kh[(size_t)(k0 + kt4 * 16 + l15) * DKV + kk0]);
                s[kt4] = __builtin_amdgcn_mfma_f32_16x16x32_bf16(
                    ka, (ks == 0) ? qB0 : qB1, s[kt4], 0, 0, 0);
            }
        }

        if (kt == qt) {   // wave-uniform: only the diagonal tile masks
            const int qi = w * 16 + l15;
            #pragma unroll
            for (int kt4 = 0; kt4 < 4; ++kt4)
                #pragma unroll
                for (int r = 0; r < 4; ++r)
                    if ((kt4 * 16 + quad * 4 + r) > qi) s[kt4][r] = -1e30f;
        }

        // exp2 + pack P^T B-frags
        u32 pb[4][2];
        #pragma unroll
        for (int kt4 = 0; kt4 < 4; ++kt4) {
            float p[4];
            #pragma unroll
            for (int r = 0; r < 4; ++r) {
                p[r] = exp2f(s[kt4][r] - 24.0f);
                lpart += p[r];
            }
            pb[kt4][0] = __builtin_amdgcn_perm(fbits(p[1]), fbits(p[0]), 0x07060302u);
            pb[kt4][1] = __builtin_amdgcn_perm(fbits(p[3]), fbits(p[2]), 0x07060302u);
        }

        // O^T += V^T . P^T, V frags direct from L1/L2
        #pragma unroll
        for (int pair = 0; pair < 2; ++pair) {
            union { bf16x8 v; u32 u[4]; } pu;
            pu.u[0] = pb[pair * 2][0];     pu.u[1] = pb[pair * 2][1];
            pu.u[2] = pb[pair * 2 + 1][0]; pu.u[3] = pb[pair * 2 + 1][1];
            const int kk0 = (quad * 2 + pair) * 8;   // interleaved V column octet
            #pragma unroll
            for (int dt = 0; dt < 4; ++dt) {
                bf16x8 va = *reinterpret_cast<const bf16x8*>(
                    &Vh[(size_t)(dt * 16 + l15) * 2048 + k0 + kk0]);
                o[dt] = __builtin_amdgcn_mfma_f32_16x16x32_bf16(va, pu.v, o[dt], 0, 0, 0);
            }
        }
    }

    lpart += __shfl_xor(lpart, 16);
    lpart += __shfl_xor(lpart, 32);
    float inv = 1.0f / lpart;

    #pragma unroll
    for (int dt = 0; dt < 4; ++dt) {
        ushort4 ov;
        ov.x = f2b(o[dt][0] * inv);
        ov.y = f2b(o[dt][1] * inv);
        ov.z = f2b(o[dt][2] * inv);
        ov.w = f2b(o[dt][3] * inv);
        *reinterpret_cast<ushort4*>(attnb + (size_t)qrow * DQ + h * HD + dt * 16 + quad * 4) = ov;
    }
}

// ---------------------------------------------------------------------------
extern "C" void kernel_launch(void* const* d_in, const int* in_sizes, int n_in,
                              void* d_out, int out_size, void* d_ws, size_t ws_size,
                              hipStream_t stream) {
    const float* x    = (const float*)d_in[0];
    const float* cosb = (const float*)d_in[1];
    const float* sinb = (const float*)d_in[2];
    const float* wq   = (const float*)d_in[3];
    const float* wk   = (const float*)d_in[4];
    const float* wv   = (const float*)d_in[5];
    const float* wo   = (const float*)d_in[6];
    const float* qnw  = (const float*)d_in[7];
    const float* knw  = (const float*)d_in[8];
    float* out = (float*)d_out;

    char* ws = (char*)d_ws;
    const size_t MB = 1024 * 1024;
    u16* xb    = (u16*)(ws + 0);          // 8 MB
    u16* wqkvT = (u16*)(ws + 8  * MB);    // 12 MB: [wq^T; wk^T; wv^T] [3072][2048]
    u16* woT   = (u16*)(ws + 20 * MB);    // 8 MB
    u16* Qb    = (u16*)(ws + 28 * MB);    // 8 MB
    u16* Kb    = (u16*)(ws + 36 * MB);    // 2 MB
    u16* VtG   = (u16*)(ws + 38 * MB);    // 2 MB  [512][2048] col-interleaved
    u16* attnb = (u16*)(ws + 40 * MB);    // 8 MB
    u16* Pq    = (u16*)(ws + 48 * MB);    // 2 x 12 MB bf16 QKV partials

    // 1) prep: cast x + weight transposes
    prep<<<14336, 256, 0, stream>>>(x, wq, wk, wv, wo, xb, wqkvT, woT);

    // 2a) QKV projection, split-K=2, bf16 partials: 768 blocks = 3/CU
    gemm_splitk<<<dim3(3072 / 128, SEQLEN / 128, 2), 256, 0, stream>>>(
        xb, wqkvT, Pq);

    // 2b) reduce + fused RMSNorm/RoPE/V-interleave epilogue
    qkv_reduce<<<dim3(SEQLEN / 64, 48), 256, 0, stream>>>(
        Pq, Qb, Kb, VtG, cosb, sinb, qnw, knw);

    // 3) GQA causal flash attention v8: zero-LDS, barrier-free, L2-direct
    attn_fused<<<1024, 256, 0, stream>>>(Qb, Kb, VtG, attnb);

    // 4) output projection (direct fp32 out)
    gemm_out<<<dim3(DIN / 128, SEQLEN / 64), 256, 0, stream>>>(
        attnb, woT, out);
}

// Round 12
// 270.300 us; speedup vs baseline: 1.3523x; 1.3523x over previous
//
#include <hip/hip_runtime.h>
#include <math.h>

#define SEQLEN 2048
#define DIN 2048
#define NH 32
#define NKV 8
#define HD 64
#define DQ (NH*HD)    // 2048
#define DKV (NKV*HD)  // 512

using u16 = unsigned short;
using u32 = unsigned int;
using bf16x8 = __attribute__((ext_vector_type(8))) __bf16;
using f32x4  = __attribute__((ext_vector_type(4))) float;

__device__ __forceinline__ u16 f2b(float f) {
    union { float f; u32 u; } x; x.f = f;
    u32 u = x.u;
    u32 r = (u + 0x7fffu + ((u >> 16) & 1u)) >> 16;   // RNE
    return (u16)r;
}
__device__ __forceinline__ float b2f(u16 h) {
    union { u32 u; float f; } x; x.u = (u32)h << 16; return x.f;
}
__device__ __forceinline__ u32 fbits(float f) {
    union { float f; u32 u; } x; x.f = f; return x.u;
}

// async global->LDS, 16B/lane; lds base wave-uniform, lane i writes i*16B.
__device__ __forceinline__ void gl2lds16(const u16* g, u16* l) {
    __builtin_amdgcn_global_load_lds(
        (const __attribute__((address_space(1))) void*)g,
        (__attribute__((address_space(3))) void*)l,
        16, 0, 0);
}

// --- 8-row x 64-k chunks (512 u16) for attention tiles ----------------------
__device__ __forceinline__ int lds_off(int row, int kk0) {
    return (row >> 3) * 512 + (kk0 >> 3) * 64 + (row & 7) * 8;
}
// --- 16-row x 32-k chunks (512 u16) for GEMM tiles --------------------------
__device__ __forceinline__ int lds_off32(int row, int kk0) {
    return (row >> 4) * 512 + (kk0 >> 3) * 128 + (row & 15) * 8;
}

// ---------------------------------------------------------------------------
// Fused prep: cast x -> bf16; transpose-cast wq/wk/wv (contiguous [3072][2048])
// and wo.
// ---------------------------------------------------------------------------
__global__ __launch_bounds__(256) void prep(const float* __restrict__ x,
                                            const float* __restrict__ wq,
                                            const float* __restrict__ wk,
                                            const float* __restrict__ wv,
                                            const float* __restrict__ wo,
                                            u16* __restrict__ xb,
                                            u16* __restrict__ wqkvT,
                                            u16* __restrict__ woT) {
    const int b = blockIdx.x;
    const int t = threadIdx.x;
    if (b < 4096) {
        int i = b * 1024 + t * 4;
        float4 v = *reinterpret_cast<const float4*>(&x[i]);
        ushort4 o;
        o.x = f2b(v.x); o.y = f2b(v.y); o.z = f2b(v.z); o.w = f2b(v.w);
        *reinterpret_cast<ushort4*>(&xb[i]) = o;
        return;
    }
    __shared__ float tile[32][33];
    int b2 = b - 4096;
    const float* src; u16* dst; int C, bx, by;
    if (b2 < 4096)      { src = wq; dst = wqkvT;                           C = 2048; bx = b2 & 63; by = b2 >> 6; }
    else if (b2 < 5120) { b2 -= 4096; src = wk; dst = wqkvT + (size_t)2048 * 2048; C = 512; bx = b2 & 15; by = b2 >> 4; }
    else if (b2 < 6144) { b2 -= 5120; src = wv; dst = wqkvT + (size_t)2560 * 2048; C = 512; bx = b2 & 15; by = b2 >> 4; }
    else                { b2 -= 6144; src = wo; dst = woT;                 C = 2048; bx = b2 & 63; by = b2 >> 6; }
    const int c0 = bx * 32, r0 = by * 32;
    const int tr = t >> 5, tc = t & 31;
    #pragma unroll
    for (int i = 0; i < 4; ++i)
        tile[tr + i * 8][tc] = src[(size_t)(r0 + tr + i * 8) * C + c0 + tc];
    __syncthreads();
    #pragma unroll
    for (int i = 0; i < 4; ++i)
        dst[(size_t)(c0 + tr + i * 8) * 2048 + r0 + tc] = f2b(tile[tc][tr + i * 8]);
}

// ---------------------------------------------------------------------------
// QKV GEMM v10 (verified 58.4us): SPLIT-K=2 thick loop with BF16 partials.
// BM=BN=128, 16 MFMA + 8 b128 ds_read per wave-step, counted depth-2 (3
// bufs). Grid (24,16,2)=768 = 3/CU.
// ---------------------------------------------------------------------------
__global__ __launch_bounds__(256) void gemm_splitk(const u16* __restrict__ A,
                                                   const u16* __restrict__ Bt,
                                                   u16* __restrict__ P) {
    __shared__ u16 As[3][128 * 32];   // 3 bufs x 8KB
    __shared__ u16 Bs[3][128 * 32];   // 3 bufs x 8KB  (48KB total)
    const int t = threadIdx.x;
    const int w = t >> 6, lane = t & 63, quad = lane >> 4, l15 = lane & 15;
    const int m0 = blockIdx.y * 128, n0 = blockIdx.x * 128;
    const int kb = blockIdx.z << 10;                 // 0 or 1024
    u16* Cp = P + (size_t)blockIdx.z * (2048 * 3072);
    const int wr = (w >> 1) * 64, wc = (w & 1) * 64;
    const int srow = lane & 15, skoct = (lane >> 4) * 8;
    const int K = 2048, N = 3072;

    f32x4 acc[4][4];
    #pragma unroll
    for (int mt = 0; mt < 4; ++mt)
        #pragma unroll
        for (int nt = 0; nt < 4; ++nt)
            #pragma unroll
            for (int r = 0; r < 4; ++r) acc[mt][nt][r] = 0.0f;

    auto stage = [&](int buf, int st) {
        const int k0 = st << 5;
        #pragma unroll
        for (int i = 0; i < 2; ++i) {
            int c = w * 2 + i;
            gl2lds16(A  + (size_t)(m0 + c * 16 + srow) * K + kb + k0 + skoct, &As[buf][c * 512]);
            gl2lds16(Bt + (size_t)(n0 + c * 16 + srow) * K + kb + k0 + skoct, &Bs[buf][c * 512]);
        }
    };

    const int nsteps = 32;                           // K/2 / 32
    stage(0, 0);
    stage(1, 1);
    int cur = 0;
    for (int st = 0; st < nsteps; ++st) {
        if (st < nsteps - 1) asm volatile("s_waitcnt vmcnt(4)" ::: "memory");
        else                 asm volatile("s_waitcnt vmcnt(0)" ::: "memory");
        __builtin_amdgcn_s_barrier();
        asm volatile("" ::: "memory");               // no ds_read hoist
        if (st + 2 < nsteps) {
            int tgt = (cur == 0) ? 2 : cur - 1;      // buf (st+2)%3, read at st-1
            stage(tgt, st + 2);
        }
        const int kk0 = quad * 8;
        bf16x8 a[4], b[4];
        #pragma unroll
        for (int mt = 0; mt < 4; ++mt)
            a[mt] = *reinterpret_cast<const bf16x8*>(&As[cur][lds_off32(wr + mt * 16 + l15, kk0)]);
        #pragma unroll
        for (int nt = 0; nt < 4; ++nt)
            b[nt] = *reinterpret_cast<const bf16x8*>(&Bs[cur][lds_off32(wc + nt * 16 + l15, kk0)]);
        #pragma unroll
        for (int mt = 0; mt < 4; ++mt)
            #pragma unroll
            for (int nt = 0; nt < 4; ++nt)
                acc[mt][nt] = __builtin_amdgcn_mfma_f32_16x16x32_bf16(a[mt], b[nt], acc[mt][nt], 0, 0, 0);
        cur = (cur == 2) ? 0 : cur + 1;
    }

    #pragma unroll
    for (int mt = 0; mt < 4; ++mt)
        #pragma unroll
        for (int nt = 0; nt < 4; ++nt) {
            const int rb  = m0 + wr + mt * 16 + quad * 4;
            const int col = n0 + wc + nt * 16 + l15;
            #pragma unroll
            for (int r = 0; r < 4; ++r)
                Cp[(size_t)(rb + r) * N + col] = f2b(acc[mt][nt][r]);
        }
}

// ---------------------------------------------------------------------------
// qkv_reduce (verified): bf16 P0+P1 -> fused RMSNorm+RoPE (Q/K) or
// interleave-transpose (V). Grid (32 s-tiles, 48 heads), 256 thr.
// ---------------------------------------------------------------------------
__global__ __launch_bounds__(256) void qkv_reduce(const u16* __restrict__ P,
                                                  u16* __restrict__ Qb,
                                                  u16* __restrict__ Kb,
                                                  u16* __restrict__ VtG,
                                                  const float* __restrict__ cosb,
                                                  const float* __restrict__ sinb,
                                                  const float* __restrict__ qnw,
                                                  const float* __restrict__ knw) {
    __shared__ u16 Vl[64][64];
    const int s0 = blockIdx.x * 64;
    const int h  = blockIdx.y;                    // 0..31 Q, 32..39 K, 40..47 V
    const int t  = threadIdx.x;
    const int r  = t >> 2, q = t & 3;
    const int s  = s0 + r;

    const u16* p0 = P + (size_t)s * 3072 + h * 64 + q * 16;
    const u16* p1 = p0 + (size_t)2048 * 3072;
    float v[16];
    #pragma unroll
    for (int c = 0; c < 2; ++c) {
        uint4 a = *reinterpret_cast<const uint4*>(p0 + c * 8);
        uint4 b = *reinterpret_cast<const uint4*>(p1 + c * 8);
        const u32* aw = reinterpret_cast<const u32*>(&a);
        const u32* bw = reinterpret_cast<const u32*>(&b);
        #pragma unroll
        for (int j = 0; j < 4; ++j) {
            v[c*8 + j*2]     = b2f((u16)(aw[j] & 0xffffu)) + b2f((u16)(bw[j] & 0xffffu));
            v[c*8 + j*2 + 1] = b2f((u16)(aw[j] >> 16))     + b2f((u16)(bw[j] >> 16));
        }
    }

    if (h >= 40) {                                // ---- V ----
        const int a4 = (r >> 4) & 3, b4 = (r >> 2) & 3;
        const int cl = (b4 * 2 + (a4 >> 1)) * 8 + (a4 & 1) * 4 + (r & 3);
        #pragma unroll
        for (int i = 0; i < 16; ++i) Vl[q * 16 + i][cl] = f2b(v[i]);
        __syncthreads();
        u16* dst = VtG + (size_t)((h - 40) * 64 + r) * 2048 + s0 + q * 16;
        #pragma unroll
        for (int i = 0; i < 4; ++i)
            *reinterpret_cast<ushort4*>(dst + i * 4) =
                *reinterpret_cast<const ushort4*>(&Vl[r][q * 16 + i * 4]);
        return;
    }

    const bool isQ = h < 32;
    const float* nw = isQ ? qnw : knw;
    float s2 = 0.0f;
    #pragma unroll
    for (int i = 0; i < 16; ++i) s2 += v[i] * v[i];
    s2 += __shfl_xor(s2, 1);
    s2 += __shfl_xor(s2, 2);
    const float rin = rsqrtf(s2 * (1.0f / 64.0f) + 1e-6f);

    float vn[16];
    #pragma unroll
    for (int i = 0; i < 16; ++i) vn[i] = v[i] * rin * nw[q * 16 + i];

    const float sgn = (q < 2) ? -1.0f : 1.0f;     // rotate_half sign
    float res[16];
    #pragma unroll
    for (int i = 0; i < 16; ++i) {
        const int d = q * 16 + i;
        float c  = cosb[s * 64 + d];
        float sn = sinb[s * 64 + d];
        float vp = __shfl_xor(vn[i], 2);          // partner d^32
        res[i] = vn[i] * c + sgn * vp * sn;
    }

    u16* dst;
    if (isQ) {
        #pragma unroll
        for (int i = 0; i < 16; ++i) res[i] *= 0.18033688f;   // 0.125*log2(e)
        dst = Qb + (size_t)s * 2048 + h * 64 + q * 16;
    } else {
        dst = Kb + (size_t)s * 512 + (h - 32) * 64 + q * 16;
    }
    #pragma unroll
    for (int i = 0; i < 4; ++i) {
        ushort4 o;
        o.x = f2b(res[i*4+0]); o.y = f2b(res[i*4+1]);
        o.z = f2b(res[i*4+2]); o.w = f2b(res[i*4+3]);
        *reinterpret_cast<ushort4*>(dst + i * 4) = o;
    }
}

// ---------------------------------------------------------------------------
// Out-projection GEMM (r8-verbatim). BM=64, BN=128, counted depth-2 (3
// bufs), grid (16,32) = 512 = 2/CU, fp32 C direct to out.
// ---------------------------------------------------------------------------
__global__ __launch_bounds__(256) void gemm_out(const u16* __restrict__ A,
                                                const u16* __restrict__ Bt,
                                                float* __restrict__ Cf) {
    __shared__ u16 As[3][64 * 32];    // 3 x 4KB
    __shared__ u16 Bs[3][128 * 32];   // 3 x 8KB  (36KB total)
    const int t = threadIdx.x;
    const int w = t >> 6, lane = t & 63, quad = lane >> 4, l15 = lane & 15;
    const int m0 = blockIdx.y * 64, n0 = blockIdx.x * 128;
    const int wr = (w >> 1) * 32, wc = (w & 1) * 64;
    const int srow = lane & 15, skoct = (lane >> 4) * 8;
    const int K = 2048, N = 2048;

    f32x4 acc[2][4];
    #pragma unroll
    for (int mt = 0; mt < 2; ++mt)
        #pragma unroll
        for (int nt = 0; nt < 4; ++nt)
            #pragma unroll
            for (int r = 0; r < 4; ++r) acc[mt][nt][r] = 0.0f;

    auto stage = [&](int buf, int st) {
        const int k0 = st << 5;
        gl2lds16(A + (size_t)(m0 + w * 16 + srow) * K + k0 + skoct, &As[buf][w * 512]);
        #pragma unroll
        for (int i = 0; i < 2; ++i) {
            int c = w * 2 + i;
            gl2lds16(Bt + (size_t)(n0 + c * 16 + srow) * K + k0 + skoct, &Bs[buf][c * 512]);
        }
    };

    const int nsteps = K >> 5;                       // 64
    stage(0, 0);
    stage(1, 1);
    int cur = 0;
    for (int st = 0; st < nsteps; ++st) {
        if (st < nsteps - 1) asm volatile("s_waitcnt vmcnt(3)" ::: "memory");
        else                 asm volatile("s_waitcnt vmcnt(0)" ::: "memory");
        __builtin_amdgcn_s_barrier();
        asm volatile("" ::: "memory");
        if (st + 2 < nsteps) {
            int tgt = (cur == 0) ? 2 : cur - 1;
            stage(tgt, st + 2);
        }
        const int kk0 = quad * 8;
        bf16x8 a[2], b[4];
        #pragma unroll
        for (int mt = 0; mt < 2; ++mt)
            a[mt] = *reinterpret_cast<const bf16x8*>(&As[cur][lds_off32(wr + mt * 16 + l15, kk0)]);
        #pragma unroll
        for (int nt = 0; nt < 4; ++nt)
            b[nt] = *reinterpret_cast<const bf16x8*>(&Bs[cur][lds_off32(wc + nt * 16 + l15, kk0)]);
        #pragma unroll
        for (int mt = 0; mt < 2; ++mt)
            #pragma unroll
            for (int nt = 0; nt < 4; ++nt)
                acc[mt][nt] = __builtin_amdgcn_mfma_f32_16x16x32_bf16(a[mt], b[nt], acc[mt][nt], 0, 0, 0);
        cur = (cur == 2) ? 0 : cur + 1;
    }

    #pragma unroll
    for (int mt = 0; mt < 2; ++mt)
        #pragma unroll
        for (int nt = 0; nt < 4; ++nt) {
            const int rb  = m0 + wr + mt * 16 + quad * 4;
            const int col = n0 + wc + nt * 16 + l15;
            #pragma unroll
            for (int r = 0; r < 4; ++r)
                Cf[(size_t)(rb + r) * N + col] = acc[mt][nt][r];
        }
}

// ---------------------------------------------------------------------------
// MFMA flash attention v9: v5's LDS-staged structure (best measured, 58.7us
// by r10-r8 subtraction; r11's zero-LDS was 152.8 -- staging dedups 4 waves'
// reads and decouples ~200cy L2 latency) with two occupancy/balance fixes:
// (1) 2-buf 32KB LDS (was 3-buf 48KB): drain-barrier pattern (r0/r4-proven;
//     TLP > counted-vmcnt at equal structure) -> 4 blocks/CU resident.
// (2) sum-balanced qt map: g=b>>5, a=g&7, k=g>>3, qt={31-a,8+a,23-a,a}[k].
//     The 4 co-resident blocks on a CU (b = c+256k -> same a, k=0..3) total
//     66 iters (was 80 worst-CU) AND share the same head (j=b&31 equal) ->
//     warm L1/L2 for staging. Bijective over (qt, h); heavy-first dispatch.
// Block = ONE head x 64 q-rows; wave w owns q-strip w*16..w*16+15.
// Fixed-shift softmax p=exp2(s-24). PV uses FULL K=32 MFMAs via
// column-interleaved V.
// ---------------------------------------------------------------------------
__global__ __launch_bounds__(256) void attn_fused(const u16* __restrict__ Qb,
                                                  const u16* __restrict__ Kb,
                                                  const u16* __restrict__ VtG,
                                                  u16* __restrict__ attnb) {
    __shared__ u16 Ks[2][4096];   // [buf][kv 64][d 64] swizzled 8x64 chunks
    __shared__ u16 Vt[2][4096];   // [buf][d 64][kv 64 interleaved] swizzled

    const int b    = blockIdx.x;               // 1024 blocks
    const int g    = b >> 5;                   // 0..31
    const int a    = g & 7, kg = g >> 3;       // balance class, quarter
    const int qt   = (kg == 0) ? (31 - a) : (kg == 1) ? (8 + a)
                   : (kg == 2) ? (23 - a) : a;
    const int q0   = qt * 64;
    const int j    = b & 31;
    const int kvh  = j & 7;                    // == XCD (round-robin)
    const int h    = kvh * 4 + (j >> 3);
    const int t    = threadIdx.x;
    const int w    = t >> 6, lane = t & 63, quad = lane >> 4, l15 = lane & 15;
    const int srow = lane & 7, soct = (lane >> 3) * 8;
    const int qrow = q0 + w * 16 + l15;

    const u16* qr = Qb + (size_t)qrow * DQ + h * HD;
    bf16x8 qB0, qB1;
    qB0 = *reinterpret_cast<const bf16x8*>(qr + quad * 8);
    qB1 = *reinterpret_cast<const bf16x8*>(qr + 32 + quad * 8);

    f32x4 o[4];
    #pragma unroll
    for (int dt = 0; dt < 4; ++dt)
        #pragma unroll
        for (int r = 0; r < 4; ++r) o[dt][r] = 0.0f;
    float lpart = 0.0f;

    auto stage = [&](int buf, int kt) {
        const int k0 = kt * 64;
        #pragma unroll
        for (int i = 0; i < 2; ++i) {
            int c = w * 2 + i;
            gl2lds16(Kb  + (size_t)(k0 + c * 8 + srow) * DKV + kvh * HD + soct, &Ks[buf][c * 512]);
            gl2lds16(VtG + (size_t)(kvh * HD + c * 8 + srow) * 2048 + k0 + soct, &Vt[buf][c * 512]);
        }
    };

    stage(0, 0);
    for (int kt = 0; kt <= qt; ++kt) {
        const int cur = kt & 1;
        asm volatile("s_waitcnt vmcnt(0)" ::: "memory");   // stage(kt) landed
        __builtin_amdgcn_s_barrier();
        asm volatile("" ::: "memory");
        if (kt < qt) stage(cur ^ 1, kt + 1);   // other buf; reads of cur follow
        const u16* ksb = Ks[cur];
        const u16* vtb = Vt[cur];

        // S^T = K . Q^T  (16 q x 64 kv per wave)
        f32x4 s[4];
        #pragma unroll
        for (int kt4 = 0; kt4 < 4; ++kt4)
            #pragma unroll
            for (int r = 0; r < 4; ++r) s[kt4][r] = 0.0f;
        #pragma unroll
        for (int ks = 0; ks < 2; ++ks) {
            const int kk0 = ks * 32 + quad * 8;
            #pragma unroll
            for (int kt4 = 0; kt4 < 4; ++kt4) {
                bf16x8 ka = *reinterpret_cast<const bf16x8*>(&ksb[lds_off(kt4 * 16 + l15, kk0)]);
                s[kt4] = __builtin_amdgcn_mfma_f32_16x16x32_bf16(
                    ka, (ks == 0) ? qB0 : qB1, s[kt4], 0, 0, 0);
            }
        }

        if (kt == qt) {   // wave-uniform: only the diagonal tile masks
            const int qi = w * 16 + l15;
            #pragma unroll
            for (int kt4 = 0; kt4 < 4; ++kt4)
                #pragma unroll
                for (int r = 0; r < 4; ++r)
                    if ((kt4 * 16 + quad * 4 + r) > qi) s[kt4][r] = -1e30f;
        }

        // exp2 + pack P^T B-frags
        u32 pb[4][2];
        #pragma unroll
        for (int kt4 = 0; kt4 < 4; ++kt4) {
            float p[4];
            #pragma unroll
            for (int r = 0; r < 4; ++r) {
                p[r] = exp2f(s[kt4][r] - 24.0f);
                lpart += p[r];
            }
            pb[kt4][0] = __builtin_amdgcn_perm(fbits(p[1]), fbits(p[0]), 0x07060302u);
            pb[kt4][1] = __builtin_amdgcn_perm(fbits(p[3]), fbits(p[2]), 0x07060302u);
        }

        // O^T += V^T . P^T : 2 pairs x 4 dt, full-K=32 MFMAs
        #pragma unroll
        for (int pair = 0; pair < 2; ++pair) {
            union { bf16x8 v; u32 u[4]; } pu;
            pu.u[0] = pb[pair * 2][0];     pu.u[1] = pb[pair * 2][1];
            pu.u[2] = pb[pair * 2 + 1][0]; pu.u[3] = pb[pair * 2 + 1][1];
            const int kk0 = (quad * 2 + pair) * 8;   // interleaved V column octet
            #pragma unroll
            for (int dt = 0; dt < 4; ++dt) {
                bf16x8 va = *reinterpret_cast<const bf16x8*>(&vtb[lds_off(dt * 16 + l15, kk0)]);
                o[dt] = __builtin_amdgcn_mfma_f32_16x16x32_bf16(va, pu.v, o[dt], 0, 0, 0);
            }
        }
    }

    lpart += __shfl_xor(lpart, 16);
    lpart += __shfl_xor(lpart, 32);
    float inv = 1.0f / lpart;

    #pragma unroll
    for (int dt = 0; dt < 4; ++dt) {
        ushort4 ov;
        ov.x = f2b(o[dt][0] * inv);
        ov.y = f2b(o[dt][1] * inv);
        ov.z = f2b(o[dt][2] * inv);
        ov.w = f2b(o[dt][3] * inv);
        *reinterpret_cast<ushort4*>(attnb + (size_t)qrow * DQ + h * HD + dt * 16 + quad * 4) = ov;
    }
}

// ---------------------------------------------------------------------------
extern "C" void kernel_launch(void* const* d_in, const int* in_sizes, int n_in,
                              void* d_out, int out_size, void* d_ws, size_t ws_size,
                              hipStream_t stream) {
    const float* x    = (const float*)d_in[0];
    const float* cosb = (const float*)d_in[1];
    const float* sinb = (const float*)d_in[2];
    const float* wq   = (const float*)d_in[3];
    const float* wk   = (const float*)d_in[4];
    const float* wv   = (const float*)d_in[5];
    const float* wo   = (const float*)d_in[6];
    const float* qnw  = (const float*)d_in[7];
    const float* knw  = (const float*)d_in[8];
    float* out = (float*)d_out;

    char* ws = (char*)d_ws;
    const size_t MB = 1024 * 1024;
    u16* xb    = (u16*)(ws + 0);          // 8 MB
    u16* wqkvT = (u16*)(ws + 8  * MB);    // 12 MB: [wq^T; wk^T; wv^T] [3072][2048]
    u16* woT   = (u16*)(ws + 20 * MB);    // 8 MB
    u16* Qb    = (u16*)(ws + 28 * MB);    // 8 MB
    u16* Kb    = (u16*)(ws + 36 * MB);    // 2 MB
    u16* VtG   = (u16*)(ws + 38 * MB);    // 2 MB  [512][2048] col-interleaved
    u16* attnb = (u16*)(ws + 40 * MB);    // 8 MB
    u16* Pq    = (u16*)(ws + 48 * MB);    // 2 x 12 MB bf16 QKV partials

    // 1) prep: cast x + weight transposes
    prep<<<14336, 256, 0, stream>>>(x, wq, wk, wv, wo, xb, wqkvT, woT);

    // 2a) QKV projection, split-K=2, bf16 partials: 768 blocks = 3/CU
    gemm_splitk<<<dim3(3072 / 128, SEQLEN / 128, 2), 256, 0, stream>>>(
        xb, wqkvT, Pq);

    // 2b) reduce + fused RMSNorm/RoPE/V-interleave epilogue
    qkv_reduce<<<dim3(SEQLEN / 64, 48), 256, 0, stream>>>(
        Pq, Qb, Kb, VtG, cosb, sinb, qnw, knw);

    // 3) GQA causal flash attention v9: 2-buf 32KB, balanced qt, 4 blocks/CU
    attn_fused<<<1024, 256, 0, stream>>>(Qb, Kb, VtG, attnb);

    // 4) output projection (direct fp32 out)
    gemm_out<<<dim3(DIN / 128, SEQLEN / 64), 256, 0, stream>>>(
        attnb, woT, out);
}

// Round 13
// 262.214 us; speedup vs baseline: 1.3940x; 1.0308x over previous
//
#include <hip/hip_runtime.h>
#include <math.h>

#define SEQLEN 2048
#define DIN 2048
#define NH 32
#define NKV 8
#define HD 64
#define DQ (NH*HD)    // 2048
#define DKV (NKV*HD)  // 512

using u16 = unsigned short;
using u32 = unsigned int;
using bf16x8 = __attribute__((ext_vector_type(8))) __bf16;
using f32x4  = __attribute__((ext_vector_type(4))) float;

__device__ __forceinline__ u16 f2b(float f) {
    union { float f; u32 u; } x; x.f = f;
    u32 u = x.u;
    u32 r = (u + 0x7fffu + ((u >> 16) & 1u)) >> 16;   // RNE
    return (u16)r;
}
__device__ __forceinline__ float b2f(u16 h) {
    union { u32 u; float f; } x; x.u = (u32)h << 16; return x.f;
}
__device__ __forceinline__ u32 fbits(float f) {
    union { float f; u32 u; } x; x.f = f; return x.u;
}

// Raw hardware 2^x (single v_exp_f32; OCML exp2f wraps it with extra VALU).
__device__ __forceinline__ float exp2_hw(float x) {
#if __has_builtin(__builtin_amdgcn_exp2f)
    return __builtin_amdgcn_exp2f(x);
#else
    return exp2f(x);
#endif
}

// async global->LDS, 16B/lane; lds base wave-uniform, lane i writes i*16B.
__device__ __forceinline__ void gl2lds16(const u16* g, u16* l) {
    __builtin_amdgcn_global_load_lds(
        (const __attribute__((address_space(1))) void*)g,
        (__attribute__((address_space(3))) void*)l,
        16, 0, 0);
}

// --- 8-row x 64-k chunks (512 u16) for attention tiles ----------------------
__device__ __forceinline__ int lds_off(int row, int kk0) {
    return (row >> 3) * 512 + (kk0 >> 3) * 64 + (row & 7) * 8;
}
// --- 16-row x 32-k chunks (512 u16) for GEMM tiles --------------------------
__device__ __forceinline__ int lds_off32(int row, int kk0) {
    return (row >> 4) * 512 + (kk0 >> 3) * 128 + (row & 15) * 8;
}

// ---------------------------------------------------------------------------
// Fused prep: cast x -> bf16; transpose-cast wq/wk/wv (contiguous [3072][2048])
// and wo.
// ---------------------------------------------------------------------------
__global__ __launch_bounds__(256) void prep(const float* __restrict__ x,
                                            const float* __restrict__ wq,
                                            const float* __restrict__ wk,
                                            const float* __restrict__ wv,
                                            const float* __restrict__ wo,
                                            u16* __restrict__ xb,
                                            u16* __restrict__ wqkvT,
                                            u16* __restrict__ woT) {
    const int b = blockIdx.x;
    const int t = threadIdx.x;
    if (b < 4096) {
        int i = b * 1024 + t * 4;
        float4 v = *reinterpret_cast<const float4*>(&x[i]);
        ushort4 o;
        o.x = f2b(v.x); o.y = f2b(v.y); o.z = f2b(v.z); o.w = f2b(v.w);
        *reinterpret_cast<ushort4*>(&xb[i]) = o;
        return;
    }
    __shared__ float tile[32][33];
    int b2 = b - 4096;
    const float* src; u16* dst; int C, bx, by;
    if (b2 < 4096)      { src = wq; dst = wqkvT;                           C = 2048; bx = b2 & 63; by = b2 >> 6; }
    else if (b2 < 5120) { b2 -= 4096; src = wk; dst = wqkvT + (size_t)2048 * 2048; C = 512; bx = b2 & 15; by = b2 >> 4; }
    else if (b2 < 6144) { b2 -= 5120; src = wv; dst = wqkvT + (size_t)2560 * 2048; C = 512; bx = b2 & 15; by = b2 >> 4; }
    else                { b2 -= 6144; src = wo; dst = woT;                 C = 2048; bx = b2 & 63; by = b2 >> 6; }
    const int c0 = bx * 32, r0 = by * 32;
    const int tr = t >> 5, tc = t & 31;
    #pragma unroll
    for (int i = 0; i < 4; ++i)
        tile[tr + i * 8][tc] = src[(size_t)(r0 + tr + i * 8) * C + c0 + tc];
    __syncthreads();
    #pragma unroll
    for (int i = 0; i < 4; ++i)
        dst[(size_t)(c0 + tr + i * 8) * 2048 + r0 + tc] = f2b(tile[tc][tr + i * 8]);
}

// ---------------------------------------------------------------------------
// QKV GEMM v10 (verified 58.4us): SPLIT-K=2 thick loop with BF16 partials.
// BM=BN=128, 16 MFMA + 8 b128 ds_read per wave-step, counted depth-2 (3
// bufs). Grid (24,16,2)=768 = 3/CU.
// ---------------------------------------------------------------------------
__global__ __launch_bounds__(256) void gemm_splitk(const u16* __restrict__ A,
                                                   const u16* __restrict__ Bt,
                                                   u16* __restrict__ P) {
    __shared__ u16 As[3][128 * 32];   // 3 bufs x 8KB
    __shared__ u16 Bs[3][128 * 32];   // 3 bufs x 8KB  (48KB total)
    const int t = threadIdx.x;
    const int w = t >> 6, lane = t & 63, quad = lane >> 4, l15 = lane & 15;
    const int m0 = blockIdx.y * 128, n0 = blockIdx.x * 128;
    const int kb = blockIdx.z << 10;                 // 0 or 1024
    u16* Cp = P + (size_t)blockIdx.z * (2048 * 3072);
    const int wr = (w >> 1) * 64, wc = (w & 1) * 64;
    const int srow = lane & 15, skoct = (lane >> 4) * 8;
    const int K = 2048, N = 3072;

    f32x4 acc[4][4];
    #pragma unroll
    for (int mt = 0; mt < 4; ++mt)
        #pragma unroll
        for (int nt = 0; nt < 4; ++nt)
            #pragma unroll
            for (int r = 0; r < 4; ++r) acc[mt][nt][r] = 0.0f;

    auto stage = [&](int buf, int st) {
        const int k0 = st << 5;
        #pragma unroll
        for (int i = 0; i < 2; ++i) {
            int c = w * 2 + i;
            gl2lds16(A  + (size_t)(m0 + c * 16 + srow) * K + kb + k0 + skoct, &As[buf][c * 512]);
            gl2lds16(Bt + (size_t)(n0 + c * 16 + srow) * K + kb + k0 + skoct, &Bs[buf][c * 512]);
        }
    };

    const int nsteps = 32;                           // K/2 / 32
    stage(0, 0);
    stage(1, 1);
    int cur = 0;
    for (int st = 0; st < nsteps; ++st) {
        if (st < nsteps - 1) asm volatile("s_waitcnt vmcnt(4)" ::: "memory");
        else                 asm volatile("s_waitcnt vmcnt(0)" ::: "memory");
        __builtin_amdgcn_s_barrier();
        asm volatile("" ::: "memory");               // no ds_read hoist
        if (st + 2 < nsteps) {
            int tgt = (cur == 0) ? 2 : cur - 1;      // buf (st+2)%3, read at st-1
            stage(tgt, st + 2);
        }
        const int kk0 = quad * 8;
        bf16x8 a[4], b[4];
        #pragma unroll
        for (int mt = 0; mt < 4; ++mt)
            a[mt] = *reinterpret_cast<const bf16x8*>(&As[cur][lds_off32(wr + mt * 16 + l15, kk0)]);
        #pragma unroll
        for (int nt = 0; nt < 4; ++nt)
            b[nt] = *reinterpret_cast<const bf16x8*>(&Bs[cur][lds_off32(wc + nt * 16 + l15, kk0)]);
        #pragma unroll
        for (int mt = 0; mt < 4; ++mt)
            #pragma unroll
            for (int nt = 0; nt < 4; ++nt)
                acc[mt][nt] = __builtin_amdgcn_mfma_f32_16x16x32_bf16(a[mt], b[nt], acc[mt][nt], 0, 0, 0);
        cur = (cur == 2) ? 0 : cur + 1;
    }

    #pragma unroll
    for (int mt = 0; mt < 4; ++mt)
        #pragma unroll
        for (int nt = 0; nt < 4; ++nt) {
            const int rb  = m0 + wr + mt * 16 + quad * 4;
            const int col = n0 + wc + nt * 16 + l15;
            #pragma unroll
            for (int r = 0; r < 4; ++r)
                Cp[(size_t)(rb + r) * N + col] = f2b(acc[mt][nt][r]);
        }
}

// ---------------------------------------------------------------------------
// qkv_reduce (verified): bf16 P0+P1 -> fused RMSNorm+RoPE (Q/K) or
// interleave-transpose (V). Grid (32 s-tiles, 48 heads), 256 thr.
// ---------------------------------------------------------------------------
__global__ __launch_bounds__(256) void qkv_reduce(const u16* __restrict__ P,
                                                  u16* __restrict__ Qb,
                                                  u16* __restrict__ Kb,
                                                  u16* __restrict__ VtG,
                                                  const float* __restrict__ cosb,
                                                  const float* __restrict__ sinb,
                                                  const float* __restrict__ qnw,
                                                  const float* __restrict__ knw) {
    __shared__ u16 Vl[64][64];
    const int s0 = blockIdx.x * 64;
    const int h  = blockIdx.y;                    // 0..31 Q, 32..39 K, 40..47 V
    const int t  = threadIdx.x;
    const int r  = t >> 2, q = t & 3;
    const int s  = s0 + r;

    const u16* p0 = P + (size_t)s * 3072 + h * 64 + q * 16;
    const u16* p1 = p0 + (size_t)2048 * 3072;
    float v[16];
    #pragma unroll
    for (int c = 0; c < 2; ++c) {
        uint4 a = *reinterpret_cast<const uint4*>(p0 + c * 8);
        uint4 b = *reinterpret_cast<const uint4*>(p1 + c * 8);
        const u32* aw = reinterpret_cast<const u32*>(&a);
        const u32* bw = reinterpret_cast<const u32*>(&b);
        #pragma unroll
        for (int j = 0; j < 4; ++j) {
            v[c*8 + j*2]     = b2f((u16)(aw[j] & 0xffffu)) + b2f((u16)(bw[j] & 0xffffu));
            v[c*8 + j*2 + 1] = b2f((u16)(aw[j] >> 16))     + b2f((u16)(bw[j] >> 16));
        }
    }

    if (h >= 40) {                                // ---- V ----
        const int a4 = (r >> 4) & 3, b4 = (r >> 2) & 3;
        const int cl = (b4 * 2 + (a4 >> 1)) * 8 + (a4 & 1) * 4 + (r & 3);
        #pragma unroll
        for (int i = 0; i < 16; ++i) Vl[q * 16 + i][cl] = f2b(v[i]);
        __syncthreads();
        u16* dst = VtG + (size_t)((h - 40) * 64 + r) * 2048 + s0 + q * 16;
        #pragma unroll
        for (int i = 0; i < 4; ++i)
            *reinterpret_cast<ushort4*>(dst + i * 4) =
                *reinterpret_cast<const ushort4*>(&Vl[r][q * 16 + i * 4]);
        return;
    }

    const bool isQ = h < 32;
    const float* nw = isQ ? qnw : knw;
    float s2 = 0.0f;
    #pragma unroll
    for (int i = 0; i < 16; ++i) s2 += v[i] * v[i];
    s2 += __shfl_xor(s2, 1);
    s2 += __shfl_xor(s2, 2);
    const float rin = rsqrtf(s2 * (1.0f / 64.0f) + 1e-6f);

    float vn[16];
    #pragma unroll
    for (int i = 0; i < 16; ++i) vn[i] = v[i] * rin * nw[q * 16 + i];

    const float sgn = (q < 2) ? -1.0f : 1.0f;     // rotate_half sign
    float res[16];
    #pragma unroll
    for (int i = 0; i < 16; ++i) {
        const int d = q * 16 + i;
        float c  = cosb[s * 64 + d];
        float sn = sinb[s * 64 + d];
        float vp = __shfl_xor(vn[i], 2);          // partner d^32
        res[i] = vn[i] * c + sgn * vp * sn;
    }

    u16* dst;
    if (isQ) {
        #pragma unroll
        for (int i = 0; i < 16; ++i) res[i] *= 0.18033688f;   // 0.125*log2(e)
        dst = Qb + (size_t)s * 2048 + h * 64 + q * 16;
    } else {
        dst = Kb + (size_t)s * 512 + (h - 32) * 64 + q * 16;
    }
    #pragma unroll
    for (int i = 0; i < 4; ++i) {
        ushort4 o;
        o.x = f2b(res[i*4+0]); o.y = f2b(res[i*4+1]);
        o.z = f2b(res[i*4+2]); o.w = f2b(res[i*4+3]);
        *reinterpret_cast<ushort4*>(dst + i * 4) = o;
    }
}

// ---------------------------------------------------------------------------
// Out-projection GEMM (r8-verbatim). BM=64, BN=128, counted depth-2 (3
// bufs), grid (16,32) = 512 = 2/CU, fp32 C direct to out.
// ---------------------------------------------------------------------------
__global__ __launch_bounds__(256) void gemm_out(const u16* __restrict__ A,
                                                const u16* __restrict__ Bt,
                                                float* __restrict__ Cf) {
    __shared__ u16 As[3][64 * 32];    // 3 x 4KB
    __shared__ u16 Bs[3][128 * 32];   // 3 x 8KB  (36KB total)
    const int t = threadIdx.x;
    const int w = t >> 6, lane = t & 63, quad = lane >> 4, l15 = lane & 15;
    const int m0 = blockIdx.y * 64, n0 = blockIdx.x * 128;
    const int wr = (w >> 1) * 32, wc = (w & 1) * 64;
    const int srow = lane & 15, skoct = (lane >> 4) * 8;
    const int K = 2048, N = 2048;

    f32x4 acc[2][4];
    #pragma unroll
    for (int mt = 0; mt < 2; ++mt)
        #pragma unroll
        for (int nt = 0; nt < 4; ++nt)
            #pragma unroll
            for (int r = 0; r < 4; ++r) acc[mt][nt][r] = 0.0f;

    auto stage = [&](int buf, int st) {
        const int k0 = st << 5;
        gl2lds16(A + (size_t)(m0 + w * 16 + srow) * K + k0 + skoct, &As[buf][w * 512]);
        #pragma unroll
        for (int i = 0; i < 2; ++i) {
            int c = w * 2 + i;
            gl2lds16(Bt + (size_t)(n0 + c * 16 + srow) * K + k0 + skoct, &Bs[buf][c * 512]);
        }
    };

    const int nsteps = K >> 5;                       // 64
    stage(0, 0);
    stage(1, 1);
    int cur = 0;
    for (int st = 0; st < nsteps; ++st) {
        if (st < nsteps - 1) asm volatile("s_waitcnt vmcnt(3)" ::: "memory");
        else                 asm volatile("s_waitcnt vmcnt(0)" ::: "memory");
        __builtin_amdgcn_s_barrier();
        asm volatile("" ::: "memory");
        if (st + 2 < nsteps) {
            int tgt = (cur == 0) ? 2 : cur - 1;
            stage(tgt, st + 2);
        }
        const int kk0 = quad * 8;
        bf16x8 a[2], b[4];
        #pragma unroll
        for (int mt = 0; mt < 2; ++mt)
            a[mt] = *reinterpret_cast<const bf16x8*>(&As[cur][lds_off32(wr + mt * 16 + l15, kk0)]);
        #pragma unroll
        for (int nt = 0; nt < 4; ++nt)
            b[nt] = *reinterpret_cast<const bf16x8*>(&Bs[cur][lds_off32(wc + nt * 16 + l15, kk0)]);
        #pragma unroll
        for (int mt = 0; mt < 2; ++mt)
            #pragma unroll
            for (int nt = 0; nt < 4; ++nt)
                acc[mt][nt] = __builtin_amdgcn_mfma_f32_16x16x32_bf16(a[mt], b[nt], acc[mt][nt], 0, 0, 0);
        cur = (cur == 2) ? 0 : cur + 1;
    }

    #pragma unroll
    for (int mt = 0; mt < 2; ++mt)
        #pragma unroll
        for (int nt = 0; nt < 4; ++nt) {
            const int rb  = m0 + wr + mt * 16 + quad * 4;
            const int col = n0 + wc + nt * 16 + l15;
            #pragma unroll
            for (int r = 0; r < 4; ++r)
                Cf[(size_t)(rb + r) * N + col] = acc[mt][nt][r];
        }
}

// ---------------------------------------------------------------------------
// MFMA flash attention v10: 512-THREAD BLOCKS, TWO SIBLING HEADS PER BLOCK.
// r12 diagnosis: attn VALU/issue-bound at only ~8 resident waves/CU (Occ
// 24.5%, VALUBusy 44% >> MfmaUtil 11%); per-iter barrier/drain exposed
// (~2075cy wall vs ~600-900cy issue work per wave-iter). v10: waves 0-3 ->
// head h0, waves 4-7 -> h0+1 (same kvh): per-wave work UNCHANGED (v7's
// mistake was doubling per-wave work), but each staged K/V tile feeds 8
// waves, stage-issue per wave halves (2 loads), and residency doubles to
// 2 blocks/CU x 8 waves = 16 waves/CU. 512 blocks, heavy-first qt=31-(b>>4)
// (LPT refill). LDS 32KB (2-buf drain pattern, r0/r4-proven). Softmax:
// raw v_exp_f32 via __builtin_amdgcn_exp2f (OCML exp2f wraps it with extra
// VALU) + 4-way lpart accumulators (break 16-deep serial add chain).
// Fixed-shift softmax p=exp2(s-24). PV uses FULL K=32 MFMAs via
// column-interleaved V.
// ---------------------------------------------------------------------------
__global__ __launch_bounds__(512) void attn_fused(const u16* __restrict__ Qb,
                                                  const u16* __restrict__ Kb,
                                                  const u16* __restrict__ VtG,
                                                  u16* __restrict__ attnb) {
    __shared__ u16 Ks[2][4096];   // [buf][kv 64][d 64] swizzled 8x64 chunks
    __shared__ u16 Vt[2][4096];   // [buf][d 64][kv 64 interleaved] swizzled

    const int b    = blockIdx.x;               // 512 blocks
    const int qt   = 31 - (b >> 4);            // heavy-first (16 h-pairs each)
    const int q0   = qt * 64;
    const int j    = b & 15;
    const int kvh  = j & 7;                    // == XCD (round-robin)
    const int hp   = j >> 3;                   // head-pair within kvh
    const int t    = threadIdx.x;
    const int w    = t >> 6;                   // 0..7
    const int hs   = w >> 2;                   // head side 0/1
    const int wq_  = w & 3;                    // wave within head side
    const int h    = kvh * 4 + hp * 2 + hs;
    const int lane = t & 63, quad = lane >> 4, l15 = lane & 15;
    const int srow = lane & 7, soct = (lane >> 3) * 8;
    const int qrow = q0 + wq_ * 16 + l15;

    const u16* qr = Qb + (size_t)qrow * DQ + h * HD;
    bf16x8 qB0, qB1;
    qB0 = *reinterpret_cast<const bf16x8*>(qr + quad * 8);
    qB1 = *reinterpret_cast<const bf16x8*>(qr + 32 + quad * 8);

    f32x4 o[4];
    #pragma unroll
    for (int dt = 0; dt < 4; ++dt)
        #pragma unroll
        for (int r = 0; r < 4; ++r) o[dt][r] = 0.0f;
    f32x4 lp4;
    #pragma unroll
    for (int r = 0; r < 4; ++r) lp4[r] = 0.0f;

    // 16 chunks (8 K + 8 V) across 8 waves -> 2 loads per wave per stage.
    auto stage = [&](int buf, int kt) {
        const int k0 = kt * 64;
        gl2lds16(Kb  + (size_t)(k0 + w * 8 + srow) * DKV + kvh * HD + soct, &Ks[buf][w * 512]);
        gl2lds16(VtG + (size_t)(kvh * HD + w * 8 + srow) * 2048 + k0 + soct, &Vt[buf][w * 512]);
    };

    stage(0, 0);
    for (int kt = 0; kt <= qt; ++kt) {
        const int cur = kt & 1;
        asm volatile("s_waitcnt vmcnt(0)" ::: "memory");   // own stage loads landed
        __builtin_amdgcn_s_barrier();                      // all waves' loads landed
        asm volatile("" ::: "memory");
        if (kt < qt) stage(cur ^ 1, kt + 1);   // other buf; reads of cur follow
        const u16* ksb = Ks[cur];
        const u16* vtb = Vt[cur];

        // S^T = K . Q^T  (16 q x 64 kv per wave)
        f32x4 s[4];
        #pragma unroll
        for (int kt4 = 0; kt4 < 4; ++kt4)
            #pragma unroll
            for (int r = 0; r < 4; ++r) s[kt4][r] = 0.0f;
        #pragma unroll
        for (int ks = 0; ks < 2; ++ks) {
            const int kk0 = ks * 32 + quad * 8;
            #pragma unroll
            for (int kt4 = 0; kt4 < 4; ++kt4) {
                bf16x8 ka = *reinterpret_cast<const bf16x8*>(&ksb[lds_off(kt4 * 16 + l15, kk0)]);
                s[kt4] = __builtin_amdgcn_mfma_f32_16x16x32_bf16(
                    ka, (ks == 0) ? qB0 : qB1, s[kt4], 0, 0, 0);
            }
        }

        if (kt == qt) {   // wave-uniform: only the diagonal tile masks
            const int qi = wq_ * 16 + l15;
            #pragma unroll
            for (int kt4 = 0; kt4 < 4; ++kt4)
                #pragma unroll
                for (int r = 0; r < 4; ++r)
                    if ((kt4 * 16 + quad * 4 + r) > qi) s[kt4][r] = -1e30f;
        }

        // exp2 + pack P^T B-frags (raw v_exp_f32; 4 independent sum chains)
        u32 pb[4][2];
        #pragma unroll
        for (int kt4 = 0; kt4 < 4; ++kt4) {
            float p[4];
            #pragma unroll
            for (int r = 0; r < 4; ++r) {
                p[r] = exp2_hw(s[kt4][r] - 24.0f);
                lp4[r] += p[r];
            }
            pb[kt4][0] = __builtin_amdgcn_perm(fbits(p[1]), fbits(p[0]), 0x07060302u);
            pb[kt4][1] = __builtin_amdgcn_perm(fbits(p[3]), fbits(p[2]), 0x07060302u);
        }

        // O^T += V^T . P^T : 2 pairs x 4 dt, full-K=32 MFMAs
        #pragma unroll
        for (int pair = 0; pair < 2; ++pair) {
            union { bf16x8 v; u32 u[4]; } pu;
            pu.u[0] = pb[pair * 2][0];     pu.u[1] = pb[pair * 2][1];
            pu.u[2] = pb[pair * 2 + 1][0]; pu.u[3] = pb[pair * 2 + 1][1];
            const int kk0 = (quad * 2 + pair) * 8;   // interleaved V column octet
            #pragma unroll
            for (int dt = 0; dt < 4; ++dt) {
                bf16x8 va = *reinterpret_cast<const bf16x8*>(&vtb[lds_off(dt * 16 + l15, kk0)]);
                o[dt] = __builtin_amdgcn_mfma_f32_16x16x32_bf16(va, pu.v, o[dt], 0, 0, 0);
            }
        }
    }

    float lpart = (lp4[0] + lp4[1]) + (lp4[2] + lp4[3]);
    lpart += __shfl_xor(lpart, 16);
    lpart += __shfl_xor(lpart, 32);
    float inv = 1.0f / lpart;

    #pragma unroll
    for (int dt = 0; dt < 4; ++dt) {
        ushort4 ov;
        ov.x = f2b(o[dt][0] * inv);
        ov.y = f2b(o[dt][1] * inv);
        ov.z = f2b(o[dt][2] * inv);
        ov.w = f2b(o[dt][3] * inv);
        *reinterpret_cast<ushort4*>(attnb + (size_t)qrow * DQ + h * HD + dt * 16 + quad * 4) = ov;
    }
}

// ---------------------------------------------------------------------------
extern "C" void kernel_launch(void* const* d_in, const int* in_sizes, int n_in,
                              void* d_out, int out_size, void* d_ws, size_t ws_size,
                              hipStream_t stream) {
    const float* x    = (const float*)d_in[0];
    const float* cosb = (const float*)d_in[1];
    const float* sinb = (const float*)d_in[2];
    const float* wq   = (const float*)d_in[3];
    const float* wk   = (const float*)d_in[4];
    const float* wv   = (const float*)d_in[5];
    const float* wo   = (const float*)d_in[6];
    const float* qnw  = (const float*)d_in[7];
    const float* knw  = (const float*)d_in[8];
    float* out = (float*)d_out;

    char* ws = (char*)d_ws;
    const size_t MB = 1024 * 1024;
    u16* xb    = (u16*)(ws + 0);          // 8 MB
    u16* wqkvT = (u16*)(ws + 8  * MB);    // 12 MB: [wq^T; wk^T; wv^T] [3072][2048]
    u16* woT   = (u16*)(ws + 20 * MB);    // 8 MB
    u16* Qb    = (u16*)(ws + 28 * MB);    // 8 MB
    u16* Kb    = (u16*)(ws + 36 * MB);    // 2 MB
    u16* VtG   = (u16*)(ws + 38 * MB);    // 2 MB  [512][2048] col-interleaved
    u16* attnb = (u16*)(ws + 40 * MB);    // 8 MB
    u16* Pq    = (u16*)(ws + 48 * MB);    // 2 x 12 MB bf16 QKV partials

    // 1) prep: cast x + weight transposes
    prep<<<14336, 256, 0, stream>>>(x, wq, wk, wv, wo, xb, wqkvT, woT);

    // 2a) QKV projection, split-K=2, bf16 partials: 768 blocks = 3/CU
    gemm_splitk<<<dim3(3072 / 128, SEQLEN / 128, 2), 256, 0, stream>>>(
        xb, wqkvT, Pq);

    // 2b) reduce + fused RMSNorm/RoPE/V-interleave epilogue
    qkv_reduce<<<dim3(SEQLEN / 64, 48), 256, 0, stream>>>(
        Pq, Qb, Kb, VtG, cosb, sinb, qnw, knw);

    // 3) GQA causal flash attention v10: 512thr, 2 heads/block, 16 waves/CU
    attn_fused<<<512, 512, 0, stream>>>(Qb, Kb, VtG, attnb);

    // 4) output projection (direct fp32 out)
    gemm_out<<<dim3(DIN / 128, SEQLEN / 64), 256, 0, stream>>>(
        attnb, woT, out);
}